// Round 1
// baseline (2146.915 us; speedup 1.0000x reference)
//
#include <hip/hip_runtime.h>
#include <cstddef>

// ---------------------------------------------------------------------------
// SparseAttnLayer: BN1 -> window QKV GEMM -> 16-head windowed attention
// -> proj GEMM -> scrambled window_reverse residual -> BN2 -> MLP(1x1 convs,
// exact GELU) -> residual.  All GEMMs: bf16 MFMA 16x16x32, fp32 accum.
// ---------------------------------------------------------------------------

typedef unsigned short ushort_t;
typedef __attribute__((ext_vector_type(8))) short short8;   // 8 bf16 (4 VGPRs)
typedef __attribute__((ext_vector_type(4))) float float4v;  // MFMA acc

__device__ __forceinline__ float bf2f(unsigned short h) {
  union { unsigned int u; float f; } c; c.u = ((unsigned int)h) << 16; return c.f;
}
__device__ __forceinline__ unsigned short f2bf(float f) {
  union { float f; unsigned int u; } c; c.f = f;
  unsigned int u = c.u;
  unsigned int r = u + 0x7fffu + ((u >> 16) & 1u);   // RNE
  return (unsigned short)(r >> 16);
}
__device__ __forceinline__ void async16(const void* g, void* l) {
  __builtin_amdgcn_global_load_lds(
      (const __attribute__((address_space(1))) unsigned int*)g,
      (__attribute__((address_space(3))) unsigned int*)l, 16, 0, 0);
}

// ---------------------------------------------------------------------------
// Weight prep: Bt[n][k] = W[k][n] (bf16);  plain cast for (o,c)-layout weights
// ---------------------------------------------------------------------------
__global__ void transpose_cast(const float* __restrict__ W, ushort_t* __restrict__ Wt,
                               int K, int N) {
  int idx = blockIdx.x * 256 + threadIdx.x;
  if (idx >= K * N) return;
  int nn = idx / K, kk = idx - nn * K;
  Wt[idx] = f2bf(W[(size_t)kk * N + nn]);
}
__global__ void cast_bf(const float* __restrict__ W, ushort_t* __restrict__ Wt, int total) {
  int idx = blockIdx.x * 256 + threadIdx.x;
  if (idx < total) Wt[idx] = f2bf(W[idx]);
}

// ---------------------------------------------------------------------------
// BN1 + window partition + bf16 cast: A0[(win*64+n)][c]
// block = (window, 32-channel chunk); LDS transpose for coalesced writes
// ---------------------------------------------------------------------------
__global__ __launch_bounds__(256) void prep_qkv(
    const float* __restrict__ x, const float* __restrict__ gamma,
    const float* __restrict__ beta, const float* __restrict__ mean,
    const float* __restrict__ var, ushort_t* __restrict__ A0) {
  const int w = blockIdx.x;            // 0..2047
  const int cc0 = blockIdx.y << 5;
  const int b = w >> 8, hb = (w >> 4) & 15, wb = w & 15;
  __shared__ __align__(16) ushort_t tile[64][32];
  const int tid = threadIdx.x;
  const int ci = tid >> 3, row = tid & 7;
  const int c = cc0 + ci;
  const float a = gamma[c] * rsqrtf(var[c] + 1e-5f);
  const float sh = beta[c] - mean[c] * a;
  const float* xp = x + (((size_t)b * 512 + c) * 128 + (hb << 3) + row) * 128 + (wb << 3);
#pragma unroll
  for (int j = 0; j < 8; ++j) tile[(row << 3) + j][ci] = f2bf(xp[j] * a + sh);
  __syncthreads();
  const int n = tid >> 2, d0 = (tid & 3) << 3;
  *(uint4*)(A0 + (size_t)((w << 6) + n) * 512 + cc0 + d0) = *(const uint4*)&tile[n][d0];
}

// ---------------------------------------------------------------------------
// bf16 MFMA GEMM: C[M,N] = A[M,K] @ Bt[N,K]^T + bias  (EPI=1: exact GELU)
// 128x128 tile, BK=32, global_load_lds width-16, 4 waves x 4x4 MFMA frags
// ---------------------------------------------------------------------------
template <int EPI>
__global__ __launch_bounds__(256) void gemm_bt(
    const ushort_t* __restrict__ A, const ushort_t* __restrict__ Bt,
    const float* __restrict__ bias, ushort_t* __restrict__ C,
    int M, int N, int K) {
  __shared__ __align__(16) ushort_t lA[128 * 32];
  __shared__ __align__(16) ushort_t lB[128 * 32];
  const int tid = threadIdx.x;
  const int wave = tid >> 6, lane = tid & 63;
  const int m0 = blockIdx.y << 7, n0 = blockIdx.x << 7;
  const int wm = (wave & 1) << 6, wn = (wave >> 1) << 6;

  float4v acc[4][4];
#pragma unroll
  for (int i = 0; i < 4; ++i)
#pragma unroll
    for (int j = 0; j < 4; ++j)
#pragma unroll
      for (int r = 0; r < 4; ++r) acc[i][j][r] = 0.0f;

  const int srow = (wave << 5) + (lane >> 2);   // staging row within tile
  const int skb = (lane & 3) << 3;              // staging k offset
  const ushort_t* Ag = A + (size_t)(m0 + srow) * K + skb;
  const ushort_t* Bg = Bt + (size_t)(n0 + srow) * K + skb;
  ushort_t* lA0 = &lA[(wave << 5) * 32];
  ushort_t* lA1 = &lA[((wave << 5) + 16) * 32];
  ushort_t* lB0 = &lB[(wave << 5) * 32];
  ushort_t* lB1 = &lB[((wave << 5) + 16) * 32];
  const int fr = lane & 15;
  const int fk = (lane >> 4) << 3;

  for (int kt = 0; kt < K; kt += 32) {
    async16(Ag + kt, lA0);
    async16(Ag + kt + (size_t)16 * K, lA1);
    async16(Bg + kt, lB0);
    async16(Bg + kt + (size_t)16 * K, lB1);
    __syncthreads();
    short8 af[4], bfr[4];
#pragma unroll
    for (int i = 0; i < 4; ++i) {
      af[i] = *(const short8*)&lA[(wm + (i << 4) + fr) * 32 + fk];
      bfr[i] = *(const short8*)&lB[(wn + (i << 4) + fr) * 32 + fk];
    }
#pragma unroll
    for (int i = 0; i < 4; ++i)
#pragma unroll
      for (int j = 0; j < 4; ++j)
        acc[i][j] = __builtin_amdgcn_mfma_f32_16x16x32_bf16(af[i], bfr[j], acc[i][j], 0, 0, 0);
    __syncthreads();
  }

  const int cr = (lane >> 4) << 2;
  const int cc = lane & 15;
#pragma unroll
  for (int j = 0; j < 4; ++j) {
    const int col = n0 + wn + (j << 4) + cc;
    const float bv = bias[col];
#pragma unroll
    for (int i = 0; i < 4; ++i) {
      size_t base = (size_t)(m0 + wm + (i << 4) + cr) * N + col;
#pragma unroll
      for (int r = 0; r < 4; ++r) {
        float v = acc[i][j][r] + bv;
        if (EPI == 1) v = 0.5f * v * (1.0f + erff(v * 0.70710678118654752f));
        C[base + (size_t)r * N] = f2bf(v);
      }
    }
  }
}

// ---------------------------------------------------------------------------
// Attention: one block per (window, head). q in regs, k/v/S in LDS.
// ---------------------------------------------------------------------------
__global__ __launch_bounds__(256) void attn_kernel(
    const ushort_t* __restrict__ QKV, const float* __restrict__ table,
    ushort_t* __restrict__ OUT) {
  const int w = blockIdx.x;
  const int h = blockIdx.y;
  __shared__ __align__(16) float qs[64][36];   // pad 36 -> b128-friendly
  __shared__ __align__(16) float ks[64][36];
  __shared__ __align__(16) float vs[64][36];
  __shared__ float S[64][65];
  const int tid = threadIdx.x;
  const int n = tid >> 2, d0 = (tid & 3) << 3;
  const ushort_t* bp = QKV + (size_t)((w << 6) + n) * 1536 + h * 32 + d0;
  {
    uint4 qv = *(const uint4*)bp;
    uint4 kv = *(const uint4*)(bp + 512);
    uint4 vv = *(const uint4*)(bp + 1024);
    const unsigned int* qu = (const unsigned int*)&qv;
    const unsigned int* ku = (const unsigned int*)&kv;
    const unsigned int* vu = (const unsigned int*)&vv;
#pragma unroll
    for (int i = 0; i < 4; ++i) {
      qs[n][d0 + 2 * i]     = __uint_as_float(qu[i] << 16) * 0.17677669529663689f;
      qs[n][d0 + 2 * i + 1] = __uint_as_float(qu[i] & 0xffff0000u) * 0.17677669529663689f;
      ks[n][d0 + 2 * i]     = __uint_as_float(ku[i] << 16);
      ks[n][d0 + 2 * i + 1] = __uint_as_float(ku[i] & 0xffff0000u);
      vs[n][d0 + 2 * i]     = __uint_as_float(vu[i] << 16);
      vs[n][d0 + 2 * i + 1] = __uint_as_float(vu[i] & 0xffff0000u);
    }
  }
  __syncthreads();
  float qr[32];
#pragma unroll
  for (int d = 0; d < 32; ++d) qr[d] = qs[n][d];
  const int r1 = n >> 3, c1 = n & 7;
  const int mq = tid & 3;
  for (int s = 0; s < 16; ++s) {
    const int mm = mq + (s << 2);
    float acc = 0.f;
#pragma unroll
    for (int d = 0; d < 32; ++d) acc += qr[d] * ks[mm][d];
    const int r2 = mm >> 3, c2 = mm & 7;
    const int idx = (r1 - r2 + 7) * 15 + (c1 - c2 + 7);
    S[n][mm] = acc + table[idx * 16 + h];
  }
  __syncthreads();
  if (tid < 64) {   // one row per lane of wave 0
    float mx = -1e30f;
    for (int mm = 0; mm < 64; ++mm) mx = fmaxf(mx, S[tid][mm]);
    float sum = 0.f;
    for (int mm = 0; mm < 64; ++mm) { float e = __expf(S[tid][mm] - mx); S[tid][mm] = e; sum += e; }
    const float inv = 1.0f / sum;
    for (int mm = 0; mm < 64; ++mm) S[tid][mm] *= inv;
  }
  __syncthreads();
  float o[8];
#pragma unroll
  for (int j = 0; j < 8; ++j) o[j] = 0.f;
  for (int mm = 0; mm < 64; ++mm) {
    const float p = S[n][mm];
#pragma unroll
    for (int j = 0; j < 8; ++j) o[j] += p * vs[mm][d0 + j];
  }
  ushort_t ob[8];
#pragma unroll
  for (int j = 0; j < 8; ++j) ob[j] = f2bf(o[j]);
  *(uint4*)(OUT + (size_t)((w << 6) + n) * 512 + h * 32 + d0) = *(const uint4*)ob;
}

// ---------------------------------------------------------------------------
// Scramble gather (torch .view reinterpretation):
// out(b,c,h,w) <- PROJ flat index decomposed from F = c*16384+hb*1024+wb*64+r2*8+c2
// ---------------------------------------------------------------------------
__device__ __forceinline__ size_t scramble_idx(int b, int F) {
  const int hb0 = F >> 19, wb0 = (F >> 15) & 15;
  const int rr = (F >> 12) & 7, ccol = (F >> 9) & 7, ch = F & 511;
  return ((size_t)(b * 256 + hb0 * 16 + wb0) * 64 + rr * 8 + ccol) * 512 + ch;
}

// x1 = x + gather(PROJ); XN2 = bf16(BN2(x1)), token-major
__global__ __launch_bounds__(256) void prep_mlp(
    const float* __restrict__ x, const ushort_t* __restrict__ PROJ,
    const float* __restrict__ gamma, const float* __restrict__ beta,
    const float* __restrict__ mean, const float* __restrict__ var,
    ushort_t* __restrict__ XN2) {
  const int pc = blockIdx.x;           // 64 consecutive spatial positions
  const int cc0 = blockIdx.y << 5;
  const int p0 = pc << 6;
  const int b = p0 >> 14, hh = (p0 >> 7) & 127;
  __shared__ __align__(16) ushort_t tile[64][32];
  const int tid = threadIdx.x;
  const int ci = tid >> 3, wg = (tid & 7) << 3;
  const int c = cc0 + ci;
  const float a = gamma[c] * rsqrtf(var[c] + 1e-5f);
  const float sh = beta[c] - mean[c] * a;
  const int w0 = (p0 & 127) + wg;
  const float* xp = x + (((size_t)b * 512 + c) * 128 + hh) * 128 + w0;
  const int hb = hh >> 3, r2 = hh & 7;
#pragma unroll
  for (int j = 0; j < 8; ++j) {
    const int ww = w0 + j;
    const int F = (c << 14) + (hb << 10) + ((ww >> 3) << 6) + (r2 << 3) + (ww & 7);
    const float x1 = xp[j] + bf2f(PROJ[scramble_idx(b, F)]);
    tile[wg + j][ci] = f2bf(x1 * a + sh);
  }
  __syncthreads();
  const int i2 = tid >> 2, d0 = (tid & 3) << 3;
  *(uint4*)(XN2 + (size_t)(p0 + i2) * 512 + cc0 + d0) = *(const uint4*)&tile[i2][d0];
}

// out = x + gather(PROJ) + H2   (x1 recomputed in fp32, no 256MB x1 buffer)
__global__ __launch_bounds__(256) void final_add(
    const float* __restrict__ x, const ushort_t* __restrict__ PROJ,
    const ushort_t* __restrict__ H2, float* __restrict__ out) {
  const int pc = blockIdx.x, cc0 = blockIdx.y << 5;
  const int p0 = pc << 6;
  const int b = p0 >> 14, hh = (p0 >> 7) & 127;
  __shared__ float tile[32][65];
  const int tid = threadIdx.x;
  {
    const int i2 = tid >> 2, d0 = (tid & 3) << 3;
    const ushort_t* hp = H2 + (size_t)(p0 + i2) * 512 + cc0 + d0;
#pragma unroll
    for (int j = 0; j < 8; ++j) tile[d0 + j][i2] = bf2f(hp[j]);
  }
  __syncthreads();
  const int ci = tid >> 3, wg = (tid & 7) << 3;
  const int c = cc0 + ci;
  const int w0 = (p0 & 127) + wg;
  const float* xp = x + (((size_t)b * 512 + c) * 128 + hh) * 128 + w0;
  float* op = out + (((size_t)b * 512 + c) * 128 + hh) * 128 + w0;
  const int hb = hh >> 3, r2 = hh & 7;
#pragma unroll
  for (int j = 0; j < 8; ++j) {
    const int ww = w0 + j;
    const int F = (c << 14) + (hb << 10) + ((ww >> 3) << 6) + (r2 << 3) + (ww & 7);
    op[j] = xp[j] + bf2f(PROJ[scramble_idx(b, F)]) + tile[ci][wg + j];
  }
}

// ---------------------------------------------------------------------------
extern "C" void kernel_launch(void* const* d_in, const int* in_sizes, int n_in,
                              void* d_out, int out_size, void* d_ws, size_t ws_size,
                              hipStream_t stream) {
  const float* x      = (const float*)d_in[0];
  const float* qkv_w  = (const float*)d_in[1];
  const float* qkv_b  = (const float*)d_in[2];
  const float* proj_w = (const float*)d_in[3];
  const float* proj_b = (const float*)d_in[4];
  const float* rel_t  = (const float*)d_in[5];
  const float* bn1g = (const float*)d_in[6];
  const float* bn1b = (const float*)d_in[7];
  const float* bn1m = (const float*)d_in[8];
  const float* bn1v = (const float*)d_in[9];
  const float* w1 = (const float*)d_in[10];
  const float* b1 = (const float*)d_in[11];
  const float* w2 = (const float*)d_in[12];
  const float* b2 = (const float*)d_in[13];
  const float* bn2g = (const float*)d_in[14];
  const float* bn2b = (const float*)d_in[15];
  const float* bn2m = (const float*)d_in[16];
  const float* bn2v = (const float*)d_in[17];
  float* out = (float*)d_out;

  char* ws = (char*)d_ws;
  const size_t SZ = (size_t)131072 * 512 * 2;           // 128 MB token-major bf16
  ushort_t* WQKV  = (ushort_t*)(ws);                    // 1536x512
  ushort_t* WPROJ = (ushort_t*)(ws + 1572864);          // 512x512
  ushort_t* W1B   = (ushort_t*)(ws + 2097152);
  ushort_t* W2B   = (ushort_t*)(ws + 2621440);
  ushort_t* A0    = (ushort_t*)(ws + 3145728);          // [131072,512]
  ushort_t* QKV   = (ushort_t*)(ws + 3145728 + SZ);     // [131072,1536]
  ushort_t* OUTB  = A0;                                 // attn out (A0 dead)
  ushort_t* PROJ  = QKV;                                // QKV dead after attn
  ushort_t* XN2   = (ushort_t*)((char*)QKV + SZ);
  ushort_t* H1    = (ushort_t*)((char*)QKV + 2 * SZ);
  ushort_t* H2    = A0;                                 // OUTB dead after proj
  // peak ws use: 3145728 + 4*SZ = 540,016,640 bytes

  transpose_cast<<<(512 * 1536 + 255) / 256, 256, 0, stream>>>(qkv_w, WQKV, 512, 1536);
  transpose_cast<<<(512 * 512 + 255) / 256, 256, 0, stream>>>(proj_w, WPROJ, 512, 512);
  cast_bf<<<(512 * 512 + 255) / 256, 256, 0, stream>>>(w1, W1B, 512 * 512);
  cast_bf<<<(512 * 512 + 255) / 256, 256, 0, stream>>>(w2, W2B, 512 * 512);

  prep_qkv<<<dim3(2048, 16), 256, 0, stream>>>(x, bn1g, bn1b, bn1m, bn1v, A0);
  gemm_bt<0><<<dim3(12, 1024), 256, 0, stream>>>(A0, WQKV, qkv_b, QKV, 131072, 1536, 512);
  attn_kernel<<<dim3(2048, 16), 256, 0, stream>>>(QKV, rel_t, OUTB);
  gemm_bt<0><<<dim3(4, 1024), 256, 0, stream>>>(OUTB, WPROJ, proj_b, PROJ, 131072, 512, 512);
  prep_mlp<<<dim3(2048, 16), 256, 0, stream>>>(x, PROJ, bn2g, bn2b, bn2m, bn2v, XN2);
  gemm_bt<1><<<dim3(4, 1024), 256, 0, stream>>>(XN2, W1B, b1, H1, 131072, 512, 512);
  gemm_bt<0><<<dim3(4, 1024), 256, 0, stream>>>(H1, W2B, b2, H2, 131072, 512, 512);
  final_add<<<dim3(2048, 16), 256, 0, stream>>>(x, PROJ, H2, out);
}